// Round 12
// baseline (192.594 us; speedup 1.0000x reference)
//
#include <hip/hip_runtime.h>
#include <hip/hip_fp16.h>
#include <math.h>

#define N_NODES 100000
#define N_EDGES 1600000
#define F_IN 100
#define F_H 32

#define BKT_SHIFT 7
#define BKT_C 128                       // nodes per bucket
#define NBK 782                         // ceil(N_NODES / BKT_C)
#define BKT_CAP 2560                    // fixed bucket capacity; mean 2046, sigma 45
                                        // -> 11.4 sigma headroom (data is fixed)
// binfill: TILE/NBK = avg bucket-run length ~10.5 -- must stay >~10 for
// coalesced packed writes (round-6 2048-tile regression: run=2.6 -> +30us)
#define BF_B 1024
#define BF_EPT 8
#define BF_TILE 8192                    // BF_B * BF_EPT
#define BF_GRID 196                     // ceil(N_EDGES / BF_TILE)
// agg: 2 blocks per bucket (64 nodes each); full-slice staging, half ranking
#define AG_B 256
#define AG_EPT 9                        // 9*256=2304 >= max bucket ~2210
#define AG_HCAP 1280                    // max half-bucket ~1146 (mean 1024, sigma 32)

#define XW_B 256
#define XW_R 128                        // rows per block (== BKT_C)
#define XW_S2 51                        // LDS row stride in half2 units (102 halfs)
                                        // odd -> reads are 2-way aliased = free;
                                        // 26.1 KB -> 5 blocks/CU -> single round

// ---------------------------------------------- block-level counting sort into buckets
// gcursor[b] = relative fill count (memset 0); bucket b lives at [b*BKT_CAP, ...)
__global__ __launch_bounds__(BF_B) void binfill_kernel(
        const int* __restrict__ src, const int* __restrict__ dst,
        int* __restrict__ gcursor, unsigned* __restrict__ packed) {
    __shared__ int cnt[NBK];
    __shared__ int lbase[NBK];
    __shared__ int gbase[NBK];
    __shared__ int wsums[16];
    __shared__ unsigned stage[BF_TILE];          // 32 KB
    __shared__ unsigned short stageB[BF_TILE];   // 16 KB
    __shared__ int tot;
    int t = threadIdx.x;
    long base = (long)blockIdx.x * BF_TILE;
    for (int i = t; i < NBK; i += BF_B) cnt[i] = 0;
    __syncthreads();
    int myb[BF_EPT]; int mypos[BF_EPT]; unsigned mypk[BF_EPT];
#pragma unroll
    for (int k = 0; k < BF_EPT; k++) {
        long e = base + t + (long)k * BF_B;      // coalesced
        myb[k] = -1;
        if (e < N_EDGES) {
            int d = dst[e];
            int sI = src[e];
            int b = d >> BKT_SHIFT;
            myb[k] = b;
            mypk[k] = (unsigned)sI | ((unsigned)(d & (BKT_C - 1)) << 17);
            mypos[k] = atomicAdd(&cnt[b], 1);
        }
    }
    __syncthreads();
    // reserve global space (overlaps scan latency); cursor is relative
    if (t < NBK && cnt[t] > 0)
        gbase[t] = t * BKT_CAP + atomicAdd(&gcursor[t], cnt[t]);
    // exclusive scan of cnt[0..NBK): wave shuffle scan, 1 barrier
    int lane = t & 63, w = t >> 6;
    int v = (t < NBK) ? cnt[t] : 0;
    int sc = v;
#pragma unroll
    for (int off = 1; off < 64; off <<= 1) {
        int x = __shfl_up(sc, off, 64);
        if (lane >= off) sc += x;
    }
    if (lane == 63) wsums[w] = sc;
    __syncthreads();
    int pre = 0;
#pragma unroll
    for (int u = 0; u < 16; u++) pre += (u < w) ? wsums[u] : 0;
    int incl = sc + pre;
    if (t < NBK) lbase[t] = incl - v;
    if (t == BF_B - 1) tot = incl;
    __syncthreads();
#pragma unroll
    for (int k = 0; k < BF_EPT; k++) {
        if (myb[k] >= 0) {
            int p = lbase[myb[k]] + mypos[k];
            stage[p] = mypk[k];
            stageB[p] = (unsigned short)myb[k];
        }
    }
    __syncthreads();
    int T = tot;
    for (int i = t; i < T; i += BF_B) {          // bucket runs -> contiguous writes
        int b = stageB[i];
        packed[gbase[b] + (i - lbase[b])] = stage[i];
    }
}

// ---------------------------------------------- fused: per-bucket degree -> dinv,
// then h2(fp16) = (x @ Wc) * dinv for the same 128 rows; x staged as half2
__global__ __launch_bounds__(XW_B) void degxw_kernel(
        const int* __restrict__ blen, const unsigned* __restrict__ packed,
        const float* __restrict__ x, const float* __restrict__ W,
        float* __restrict__ dinv, __half* __restrict__ h2) {
    __shared__ __half2 xs[XW_R * XW_S2];         // 26.1 KB
    __shared__ int cnt[BKT_C];
    __shared__ float sdinv[BKT_C];
    int t = threadIdx.x;
    int b = blockIdx.x;
    // phase 1: degree histogram of this bucket's packed slice
    if (t < BKT_C) cnt[t] = 0;
    __syncthreads();
    int beg = b * BKT_CAP, end = beg + blen[b];
    for (int i = beg + t; i < end; i += XW_B)
        atomicAdd(&cnt[(packed[i] >> 17) & (BKT_C - 1)], 1);
    __syncthreads();
    int rbase = b << BKT_SHIFT;
    int rows = min(XW_R, N_NODES - rbase);
    if (t < BKT_C) {
        float dv = rsqrtf((float)cnt[t] + 1.0f);
        sdinv[t] = dv;
        if (t < rows) dinv[rbase + t] = dv;      // agg epilogue reads this
    }
    // phase 2: stage x rows (fp32 -> half2 pairs), compute h2
    int total = rows * F_IN;                     // multiple of 4
    const float4* gx4 = (const float4*)(x + (long)rbase * F_IN);
    for (int i4 = t; i4 < (total >> 2); i4 += XW_B) {
        float4 v = gx4[i4];                      // coalesced
        int i = i4 << 2;
        int r = i / F_IN;                        // float4 never crosses row (100%4==0)
        int k = i - r * F_IN;                    // even
        __half2* p = xs + r * XW_S2 + (k >> 1);
        p[0] = __floats2half2_rn(v.x, v.y);
        p[1] = __floats2half2_rn(v.z, v.w);
    }
    __syncthreads();
    int r = t & (XW_R - 1);
    // wave-uniform column half -> W loads scalarize to s_load
    int colh16 = __builtin_amdgcn_readfirstlane((t >> 7) << 4);
    if (r < rows) {
        const float* Wp = W + colh16;
        float acc[16];
#pragma unroll
        for (int j = 0; j < 16; j++) acc[j] = 0.f;
        const __half2* xr = xs + r * XW_S2;
#pragma unroll 5
        for (int k2 = 0; k2 < F_IN / 2; k2++) {
            float2 xv = __half22float2(xr[k2]);  // 1 ds_read_b32 per 32 FMAs
#pragma unroll
            for (int j = 0; j < 16; j++)
                acc[j] = fmaf(xv.y, Wp[(2 * k2 + 1) * F_H + j],
                              fmaf(xv.x, Wp[(2 * k2) * F_H + j], acc[j]));
        }
        float dv = sdinv[r];
        __half2 o[8];
#pragma unroll
        for (int j = 0; j < 8; j++)
            o[j] = __halves2half2(__float2half(acc[2 * j] * dv),
                                  __float2half(acc[2 * j + 1] * dv));
        float4* dst4 = (float4*)(h2 + (long)(rbase + r) * F_H + colh16);
        dst4[0] = ((float4*)o)[0];
        dst4[1] = ((float4*)o)[1];
    }
}

// ---------------------------------------------- per-HALF-bucket (64 nodes):
// stage full bucket slice, rank own half in LDS, 4-lane-group register gather
// (lane owns 8 cols via 16 B float4), fused MLP + log_softmax
__global__ __launch_bounds__(AG_B) void agg_kernel(
        const int* __restrict__ blen, const unsigned* __restrict__ packed,
        const __half* __restrict__ h2, const float* __restrict__ dinv,
        const float* __restrict__ bc,
        const float* __restrict__ W1, const float* __restrict__ b1,
        const float* __restrict__ W2, const float* __restrict__ b2,
        const float* __restrict__ W3, const float* __restrict__ b3,
        float* __restrict__ out) {
    __shared__ float accL[64 * 33];              // 8.4 KB; written once per node
    __shared__ int esrc[AG_HCAP];                // 5 KB node-sorted src ids
    __shared__ int cnt[64];
    __shared__ int lbase[64];                    // inclusive scan of cnt
    __shared__ float sbc[32], sW1[512], sb1[16], sW2[128], sb2[8], sW3[80], sb3[10];
    int t = threadIdx.x;
    if (t < 32) sbc[t] = bc[t];
    for (int i = t; i < 512; i += AG_B) sW1[i] = W1[i];
    if (t < 16) sb1[t] = b1[t];
    if (t < 128) sW2[t] = W2[t];
    if (t < 8) sb2[t] = b2[t];
    if (t < 80) sW3[t] = W3[t];
    if (t < 10) sb3[t] = b3[t];

    int bb = blockIdx.x >> 1;                    // bucket
    int hh = blockIdx.x & 1;                     // half (nodes hh*64 .. hh*64+63)
    int beg = bb * BKT_CAP;
    int cnum = blen[bb];                         // <= ~2210 <= AG_EPT*AG_B
    if (t < 64) cnt[t] = 0;
    __syncthreads();
    unsigned pk[AG_EPT]; int pos[AG_EPT];
#pragma unroll
    for (int k = 0; k < AG_EPT; k++) {
        int idx = t + k * AG_B;                  // coalesced full-slice read
        pk[k] = 0xFFFFFFFFu;
        if (idx < cnum) {
            unsigned p = packed[beg + idx];
            int lid7 = (p >> 17) & (BKT_C - 1);
            if ((lid7 >> 6) == hh) {             // my half only
                pk[k] = p;
                pos[k] = atomicAdd(&cnt[lid7 & 63], 1);
            }
        }
    }
    __syncthreads();
    // inclusive scan of cnt[0..63]: single-wave shuffle scan
    if (t < 64) {
        int v = cnt[t];
        int sc = v;
#pragma unroll
        for (int off = 1; off < 64; off <<= 1) {
            int xx = __shfl_up(sc, off, 64);
            if ((t & 63) >= off) sc += xx;
        }
        lbase[t] = sc;
    }
    __syncthreads();
#pragma unroll
    for (int k = 0; k < AG_EPT; k++) {
        if (pk[k] != 0xFFFFFFFFu) {
            int g = (pk[k] >> 17) & 63;
            esrc[lbase[g] - cnt[g] + pos[k]] = (int)(pk[k] & 0x1FFFF);
        }
    }
    __syncthreads();
    // group g (= t>>2) owns node g of this half; lane l (= t&3) owns cols 8l..8l+7
    {
        int g = t >> 2, l = t & 3;
        const float4* h2o = (const float4*)h2;   // row = 4 float4 (8 halfs each)
        int e = lbase[g] - cnt[g];
        int eend = lbase[g];
        float a0 = 0.f, a1 = 0.f, a2 = 0.f, a3 = 0.f;
        float a4 = 0.f, a5 = 0.f, a6 = 0.f, a7 = 0.f;
        for (; e + 8 <= eend; e += 8) {          // 8 independent 16 B gathers
            int s0 = esrc[e], s1 = esrc[e+1], s2 = esrc[e+2], s3 = esrc[e+3];
            int s4 = esrc[e+4], s5 = esrc[e+5], s6 = esrc[e+6], s7 = esrc[e+7];
            float4 q0 = h2o[s0 * 4 + l];
            float4 q1 = h2o[s1 * 4 + l];
            float4 q2 = h2o[s2 * 4 + l];
            float4 q3 = h2o[s3 * 4 + l];
            float4 q4 = h2o[s4 * 4 + l];
            float4 q5 = h2o[s5 * 4 + l];
            float4 q6 = h2o[s6 * 4 + l];
            float4 q7 = h2o[s7 * 4 + l];
#pragma unroll
            for (int u = 0; u < 8; u++) {
                float4 q = (u == 0) ? q0 : (u == 1) ? q1 : (u == 2) ? q2 :
                           (u == 3) ? q3 : (u == 4) ? q4 : (u == 5) ? q5 :
                           (u == 6) ? q6 : q7;
                const __half2* hp = (const __half2*)&q;
                float2 f0 = __half22float2(hp[0]);
                float2 f1 = __half22float2(hp[1]);
                float2 f2 = __half22float2(hp[2]);
                float2 f3 = __half22float2(hp[3]);
                a0 += f0.x; a1 += f0.y; a2 += f1.x; a3 += f1.y;
                a4 += f2.x; a5 += f2.y; a6 += f3.x; a7 += f3.y;
            }
        }
        for (; e < eend; e++) {
            float4 q = h2o[esrc[e] * 4 + l];
            const __half2* hp = (const __half2*)&q;
            float2 f0 = __half22float2(hp[0]);
            float2 f1 = __half22float2(hp[1]);
            float2 f2 = __half22float2(hp[2]);
            float2 f3 = __half22float2(hp[3]);
            a0 += f0.x; a1 += f0.y; a2 += f1.x; a3 += f1.y;
            a4 += f2.x; a5 += f2.y; a6 += f3.x; a7 += f3.y;
        }
        float* ap = accL + g * 33 + 8 * l;
        ap[0] = a0; ap[1] = a1; ap[2] = a2; ap[3] = a3;
        ap[4] = a4; ap[5] = a5; ap[6] = a6; ap[7] = a7;
    }
    __syncthreads();

    // epilogue: threads 0..63 each finish one node
    int n = (bb << BKT_SHIFT) + (hh << 6) + t;
    if (t < 64 && n < N_NODES) {
        float dv = dinv[n];
        const __half2* h2v = (const __half2*)h2;
        float a[32];
#pragma unroll
        for (int q = 0; q < 16; q++) {
            float2 hv = __half22float2(h2v[n * 16 + q]);   // self-loop term
            a[2*q]   = fmaxf((accL[t * 33 + 2*q]   + hv.x) * dv + sbc[2*q],   0.f);
            a[2*q+1] = fmaxf((accL[t * 33 + 2*q+1] + hv.y) * dv + sbc[2*q+1], 0.f);
        }
        float t1[16];
#pragma unroll
        for (int j = 0; j < 16; j++) {
            float s = sb1[j];
            for (int k = 0; k < 32; k++) s += a[k] * sW1[k * 16 + j];
            t1[j] = fmaxf(s, 0.f);
        }
        float t2[8];
#pragma unroll
        for (int j = 0; j < 8; j++) {
            float s = sb2[j];
            for (int k = 0; k < 16; k++) s += t1[k] * sW2[k * 8 + j];
            t2[j] = fmaxf(s, 0.f);
        }
        float t3[10];
#pragma unroll
        for (int j = 0; j < 10; j++) {
            float s = sb3[j];
            for (int k = 0; k < 8; k++) s += t2[k] * sW3[k * 10 + j];
            t3[j] = s;
        }
        float m = t3[0];
#pragma unroll
        for (int j = 1; j < 10; j++) m = fmaxf(m, t3[j]);
        float se = 0.f;
#pragma unroll
        for (int j = 0; j < 10; j++) se += expf(t3[j] - m);
        float lse = logf(se) + m;
        float* op = out + (long)n * 10;
#pragma unroll
        for (int j = 0; j < 10; j++) op[j] = t3[j] - lse;
    }
}

extern "C" void kernel_launch(void* const* d_in, const int* in_sizes, int n_in,
                              void* d_out, int out_size, void* d_ws, size_t ws_size,
                              hipStream_t stream) {
    const float* x  = (const float*)d_in[0];
    const int*   ei = (const int*)d_in[1];  // [2, E] int32
    const float* Wc = (const float*)d_in[3];
    const float* bc = (const float*)d_in[4];
    const float* W1 = (const float*)d_in[5];
    const float* b1 = (const float*)d_in[6];
    const float* W2 = (const float*)d_in[7];
    const float* b2 = (const float*)d_in[8];
    const float* W3 = (const float*)d_in[9];
    const float* b3 = (const float*)d_in[10];
    float* out = (float*)d_out;

    __half*   h2      = (__half*)d_ws;                          // N*32 fp16 (6.4 MB)
    unsigned* packed  = (unsigned*)((char*)d_ws + (long)N_NODES * F_H * 2);  // NBK*CAP (8 MB)
    float*    dinv    = (float*)(packed + (long)NBK * BKT_CAP); // N
    int*      gcursor = (int*)(dinv + N_NODES);                 // NBK (relative fill)

    const int* srcp = ei;
    const int* dstp = ei + N_EDGES;

    hipMemsetAsync(gcursor, 0, NBK * sizeof(int), stream);
    binfill_kernel<<<BF_GRID, BF_B, 0, stream>>>(srcp, dstp, gcursor, packed);
    degxw_kernel<<<NBK, XW_B, 0, stream>>>(gcursor, packed, x, Wc, dinv, h2);
    agg_kernel<<<NBK * 2, AG_B, 0, stream>>>(gcursor, packed, h2, dinv, bc, W1, b1,
                                             W2, b2, W3, b3, out);
}

// Round 13
// 175.153 us; speedup vs baseline: 1.0996x; 1.0996x over previous
//
#include <hip/hip_runtime.h>
#include <hip/hip_fp16.h>
#include <math.h>

#define N_NODES 100000
#define N_EDGES 1600000
#define F_IN 100
#define F_H 32

#define BKT_SHIFT 7
#define BKT_C 128                       // nodes per bucket
#define NBK 782                         // ceil(N_NODES / BKT_C)
#define BKT_CAP 2560                    // fixed bucket capacity; mean 2046, sigma 45
                                        // -> 11.4 sigma headroom (data is fixed)
// binfill: TILE/NBK = avg bucket-run length; must stay >~6 for coalesced
// packed writes (round-6: run=2.6 -> +30us). TILE 6144 -> run 7.9, grid 261
// (196-grid left 60/256 CUs idle; round-13 change)
#define BF_B 1024
#define BF_EPT 6
#define BF_TILE 6144                    // BF_B * BF_EPT
#define BF_GRID 261                     // ceil(N_EDGES / BF_TILE)
// agg: round-11 proven config (512 thr, full bucket, register gather)
#define AG_B 512
#define AG_CAP BKT_CAP                  // one chunk covers any bucket (max ~2210)
#define AG_EPT 5                        // AG_CAP / AG_B

#define XW_B 256
#define XW_R 128                        // rows per block (== BKT_C)
#define XW_S2 51                        // LDS row stride in half2 units (102 halfs)
                                        // odd -> reads 2-way aliased = free; 26.1 KB

// ---------------------------------------------- block-level counting sort into buckets
// gcursor[b] = relative fill count (memset 0); bucket b lives at [b*BKT_CAP, ...)
__global__ __launch_bounds__(BF_B) void binfill_kernel(
        const int* __restrict__ src, const int* __restrict__ dst,
        int* __restrict__ gcursor, unsigned* __restrict__ packed) {
    __shared__ int cnt[NBK];
    __shared__ int lbase[NBK];
    __shared__ int gbase[NBK];
    __shared__ int wsums[16];
    __shared__ unsigned stage[BF_TILE];          // 24 KB
    __shared__ unsigned short stageB[BF_TILE];   // 12 KB
    __shared__ int tot;
    int t = threadIdx.x;
    long base = (long)blockIdx.x * BF_TILE;
    for (int i = t; i < NBK; i += BF_B) cnt[i] = 0;
    __syncthreads();
    int myb[BF_EPT]; int mypos[BF_EPT]; unsigned mypk[BF_EPT];
#pragma unroll
    for (int k = 0; k < BF_EPT; k++) {
        long e = base + t + (long)k * BF_B;      // coalesced
        myb[k] = -1;
        if (e < N_EDGES) {
            int d = dst[e];
            int sI = src[e];
            int b = d >> BKT_SHIFT;
            myb[k] = b;
            mypk[k] = (unsigned)sI | ((unsigned)(d & (BKT_C - 1)) << 17);
            mypos[k] = atomicAdd(&cnt[b], 1);
        }
    }
    __syncthreads();
    // reserve global space (overlaps scan latency); cursor is relative
    if (t < NBK && cnt[t] > 0)
        gbase[t] = t * BKT_CAP + atomicAdd(&gcursor[t], cnt[t]);
    // exclusive scan of cnt[0..NBK): wave shuffle scan, 1 barrier
    int lane = t & 63, w = t >> 6;
    int v = (t < NBK) ? cnt[t] : 0;
    int sc = v;
#pragma unroll
    for (int off = 1; off < 64; off <<= 1) {
        int x = __shfl_up(sc, off, 64);
        if (lane >= off) sc += x;
    }
    if (lane == 63) wsums[w] = sc;
    __syncthreads();
    int pre = 0;
#pragma unroll
    for (int u = 0; u < 16; u++) pre += (u < w) ? wsums[u] : 0;
    int incl = sc + pre;
    if (t < NBK) lbase[t] = incl - v;
    if (t == BF_B - 1) tot = incl;
    __syncthreads();
#pragma unroll
    for (int k = 0; k < BF_EPT; k++) {
        if (myb[k] >= 0) {
            int p = lbase[myb[k]] + mypos[k];
            stage[p] = mypk[k];
            stageB[p] = (unsigned short)myb[k];
        }
    }
    __syncthreads();
    int T = tot;
    for (int i = t; i < T; i += BF_B) {          // bucket runs -> contiguous writes
        int b = stageB[i];
        packed[gbase[b] + (i - lbase[b])] = stage[i];
    }
}

// ---------------------------------------------- fused: per-bucket degree -> dinv,
// then h2(fp16) = (x @ Wc) * dinv; x staged as half2; single barrier
__global__ __launch_bounds__(XW_B) void degxw_kernel(
        const int* __restrict__ blen, const unsigned* __restrict__ packed,
        const float* __restrict__ x, const float* __restrict__ W,
        float* __restrict__ dinv, __half* __restrict__ h2) {
    __shared__ __half2 xs[XW_R * XW_S2];         // 26.1 KB
    __shared__ int cnt[BKT_C];
    int t = threadIdx.x;
    int b = blockIdx.x;
    if (t < BKT_C) cnt[t] = 0;
    __syncthreads();
    int rbase = b << BKT_SHIFT;
    int rows = min(XW_R, N_NODES - rbase);
    // stage x rows (fp32 -> half2) -- overlaps with the packed histogram below
    int total = rows * F_IN;                     // multiple of 4
    const float4* gx4 = (const float4*)(x + (long)rbase * F_IN);
    for (int i4 = t; i4 < (total >> 2); i4 += XW_B) {
        float4 v = gx4[i4];                      // coalesced
        int i = i4 << 2;
        int r = i / F_IN;                        // float4 never crosses row (100%4==0)
        int k = i - r * F_IN;                    // even
        __half2* p = xs + r * XW_S2 + (k >> 1);
        p[0] = __floats2half2_rn(v.x, v.y);
        p[1] = __floats2half2_rn(v.z, v.w);
    }
    // degree histogram of this bucket's packed slice
    int beg = b * BKT_CAP, end = beg + blen[b];
    for (int i = beg + t; i < end; i += XW_B)
        atomicAdd(&cnt[(packed[i] >> 17) & (BKT_C - 1)], 1);
    __syncthreads();                             // covers xs stores + cnt atomics
    int r = t & (XW_R - 1);
    float dv = rsqrtf((float)cnt[r] + 1.0f);     // per-thread recompute (no 2nd barrier)
    if (t < BKT_C && t < rows) dinv[rbase + t] = dv;  // agg epilogue reads this
    // wave-uniform column half -> W loads scalarize to s_load
    int colh16 = __builtin_amdgcn_readfirstlane((t >> 7) << 4);
    if (r < rows) {
        const float* Wp = W + colh16;
        float acc[16];
#pragma unroll
        for (int j = 0; j < 16; j++) acc[j] = 0.f;
        const __half2* xr = xs + r * XW_S2;
#pragma unroll 5
        for (int k2 = 0; k2 < F_IN / 2; k2++) {
            float2 xv = __half22float2(xr[k2]);  // 1 ds_read_b32 per 32 FMAs
#pragma unroll
            for (int j = 0; j < 16; j++)
                acc[j] = fmaf(xv.y, Wp[(2 * k2 + 1) * F_H + j],
                              fmaf(xv.x, Wp[(2 * k2) * F_H + j], acc[j]));
        }
        __half2 o[8];
#pragma unroll
        for (int j = 0; j < 8; j++)
            o[j] = __halves2half2(__float2half(acc[2 * j] * dv),
                                  __float2half(acc[2 * j + 1] * dv));
        float4* dst4 = (float4*)(h2 + (long)(rbase + r) * F_H + colh16);
        dst4[0] = ((float4*)o)[0];
        dst4[1] = ((float4*)o)[1];
    }
}

// ---------------------------------------------- per-bucket: LDS counting sort ->
// 4-lane groups (group owns ONE node; lane owns 8 cols via 16 B float4 gather;
// 16 edges per wave-inst, register accumulator) -> fused MLP + log_softmax
// [round-11 proven config; round-12 half-bucket split regressed: 2x staging]
__global__ __launch_bounds__(AG_B) void agg_kernel(
        const int* __restrict__ blen, const unsigned* __restrict__ packed,
        const __half* __restrict__ h2, const float* __restrict__ dinv,
        const float* __restrict__ bc,
        const float* __restrict__ W1, const float* __restrict__ b1,
        const float* __restrict__ W2, const float* __restrict__ b2,
        const float* __restrict__ W3, const float* __restrict__ b3,
        float* __restrict__ out) {
    __shared__ float accL[BKT_C * 33];           // 16.9 KB; written once per node
    __shared__ int esrc[AG_CAP];                 // 10.2 KB node-sorted src ids
    __shared__ int cnt[BKT_C];
    __shared__ int lbase[BKT_C];                 // inclusive scan of cnt
    __shared__ int wsum;
    __shared__ float sbc[32], sW1[512], sb1[16], sW2[128], sb2[8], sW3[80], sb3[10];
    int t = threadIdx.x;
    if (t < 32) sbc[t] = bc[t];
    if (t < 512) sW1[t] = W1[t];
    if (t < 16) sb1[t] = b1[t];
    if (t < 128) sW2[t] = W2[t];
    if (t < 8) sb2[t] = b2[t];
    if (t < 80) sW3[t] = W3[t];
    if (t < 10) sb3[t] = b3[t];

    int b = blockIdx.x;
    int beg = b * BKT_CAP;
    int cnum = blen[b];                          // <= 2210 < AG_CAP guaranteed
    if (t < BKT_C) cnt[t] = 0;
    __syncthreads();
    unsigned pk[AG_EPT]; int pos[AG_EPT];
#pragma unroll
    for (int k = 0; k < AG_EPT; k++) {
        int idx = t + k * AG_B;                  // coalesced
        pk[k] = 0xFFFFFFFFu;
        if (idx < cnum) {
            unsigned p = packed[beg + idx];
            pk[k] = p;
            pos[k] = atomicAdd(&cnt[(p >> 17) & (BKT_C - 1)], 1);
        }
    }
    __syncthreads();
    // inclusive scan of cnt[0..127]: 2-wave shuffle scan
    {
        int lane = t & 63;
        int v = 0;
        if (t < BKT_C) {
            v = cnt[t];
#pragma unroll
            for (int off = 1; off < 64; off <<= 1) {
                int xx = __shfl_up(v, off, 64);
                if (lane >= off) v += xx;
            }
            if (t == 63) wsum = v;
        }
        __syncthreads();
        if (t < BKT_C) {
            if (t >= 64) v += wsum;
            lbase[t] = v;
        }
    }
    __syncthreads();
#pragma unroll
    for (int k = 0; k < AG_EPT; k++) {
        if (pk[k] != 0xFFFFFFFFu) {
            int lid = (pk[k] >> 17) & (BKT_C - 1);
            esrc[lbase[lid] - cnt[lid] + pos[k]] = (int)(pk[k] & 0x1FFFF);
        }
    }
    __syncthreads();
    // group g (= t>>2) owns node g; lane l (= t&3) owns cols 8l..8l+7
    {
        int g = t >> 2, l = t & 3;
        const float4* h2o = (const float4*)h2;   // row = 4 float4 (8 halfs each)
        int e = lbase[g] - cnt[g];
        int eend = lbase[g];
        float a0 = 0.f, a1 = 0.f, a2 = 0.f, a3 = 0.f;
        float a4 = 0.f, a5 = 0.f, a6 = 0.f, a7 = 0.f;
        for (; e + 8 <= eend; e += 8) {          // 8 independent 16 B gathers
            int s0 = esrc[e], s1 = esrc[e+1], s2 = esrc[e+2], s3 = esrc[e+3];
            int s4 = esrc[e+4], s5 = esrc[e+5], s6 = esrc[e+6], s7 = esrc[e+7];
            float4 q0 = h2o[s0 * 4 + l];
            float4 q1 = h2o[s1 * 4 + l];
            float4 q2 = h2o[s2 * 4 + l];
            float4 q3 = h2o[s3 * 4 + l];
            float4 q4 = h2o[s4 * 4 + l];
            float4 q5 = h2o[s5 * 4 + l];
            float4 q6 = h2o[s6 * 4 + l];
            float4 q7 = h2o[s7 * 4 + l];
#pragma unroll
            for (int u = 0; u < 8; u++) {
                float4 q = (u == 0) ? q0 : (u == 1) ? q1 : (u == 2) ? q2 :
                           (u == 3) ? q3 : (u == 4) ? q4 : (u == 5) ? q5 :
                           (u == 6) ? q6 : q7;
                const __half2* hp = (const __half2*)&q;
                float2 f0 = __half22float2(hp[0]);
                float2 f1 = __half22float2(hp[1]);
                float2 f2 = __half22float2(hp[2]);
                float2 f3 = __half22float2(hp[3]);
                a0 += f0.x; a1 += f0.y; a2 += f1.x; a3 += f1.y;
                a4 += f2.x; a5 += f2.y; a6 += f3.x; a7 += f3.y;
            }
        }
        for (; e < eend; e++) {
            float4 q = h2o[esrc[e] * 4 + l];
            const __half2* hp = (const __half2*)&q;
            float2 f0 = __half22float2(hp[0]);
            float2 f1 = __half22float2(hp[1]);
            float2 f2 = __half22float2(hp[2]);
            float2 f3 = __half22float2(hp[3]);
            a0 += f0.x; a1 += f0.y; a2 += f1.x; a3 += f1.y;
            a4 += f2.x; a5 += f2.y; a6 += f3.x; a7 += f3.y;
        }
        float* ap = accL + g * 33 + 8 * l;
        ap[0] = a0; ap[1] = a1; ap[2] = a2; ap[3] = a3;
        ap[4] = a4; ap[5] = a5; ap[6] = a6; ap[7] = a7;
    }
    __syncthreads();

    // epilogue: threads 0..127 each finish one node
    int n = (b << BKT_SHIFT) + t;
    if (t < BKT_C && n < N_NODES) {
        float dv = dinv[n];
        const __half2* h2v = (const __half2*)h2;
        float a[32];
#pragma unroll
        for (int q = 0; q < 16; q++) {
            float2 hv = __half22float2(h2v[n * 16 + q]);   // self-loop term
            a[2*q]   = fmaxf((accL[t * 33 + 2*q]   + hv.x) * dv + sbc[2*q],   0.f);
            a[2*q+1] = fmaxf((accL[t * 33 + 2*q+1] + hv.y) * dv + sbc[2*q+1], 0.f);
        }
        float t1[16];
#pragma unroll
        for (int j = 0; j < 16; j++) {
            float s = sb1[j];
            for (int k = 0; k < 32; k++) s += a[k] * sW1[k * 16 + j];
            t1[j] = fmaxf(s, 0.f);
        }
        float t2[8];
#pragma unroll
        for (int j = 0; j < 8; j++) {
            float s = sb2[j];
            for (int k = 0; k < 16; k++) s += t1[k] * sW2[k * 8 + j];
            t2[j] = fmaxf(s, 0.f);
        }
        float t3[10];
#pragma unroll
        for (int j = 0; j < 10; j++) {
            float s = sb3[j];
            for (int k = 0; k < 8; k++) s += t2[k] * sW3[k * 10 + j];
            t3[j] = s;
        }
        float m = t3[0];
#pragma unroll
        for (int j = 1; j < 10; j++) m = fmaxf(m, t3[j]);
        float se = 0.f;
#pragma unroll
        for (int j = 0; j < 10; j++) se += expf(t3[j] - m);
        float lse = logf(se) + m;
        float* op = out + (long)n * 10;
#pragma unroll
        for (int j = 0; j < 10; j++) op[j] = t3[j] - lse;
    }
}

extern "C" void kernel_launch(void* const* d_in, const int* in_sizes, int n_in,
                              void* d_out, int out_size, void* d_ws, size_t ws_size,
                              hipStream_t stream) {
    const float* x  = (const float*)d_in[0];
    const int*   ei = (const int*)d_in[1];  // [2, E] int32
    const float* Wc = (const float*)d_in[3];
    const float* bc = (const float*)d_in[4];
    const float* W1 = (const float*)d_in[5];
    const float* b1 = (const float*)d_in[6];
    const float* W2 = (const float*)d_in[7];
    const float* b2 = (const float*)d_in[8];
    const float* W3 = (const float*)d_in[9];
    const float* b3 = (const float*)d_in[10];
    float* out = (float*)d_out;

    __half*   h2      = (__half*)d_ws;                          // N*32 fp16 (6.4 MB)
    unsigned* packed  = (unsigned*)((char*)d_ws + (long)N_NODES * F_H * 2);  // NBK*CAP (8 MB)
    float*    dinv    = (float*)(packed + (long)NBK * BKT_CAP); // N
    int*      gcursor = (int*)(dinv + N_NODES);                 // NBK (relative fill)

    const int* srcp = ei;
    const int* dstp = ei + N_EDGES;

    hipMemsetAsync(gcursor, 0, NBK * sizeof(int), stream);
    binfill_kernel<<<BF_GRID, BF_B, 0, stream>>>(srcp, dstp, gcursor, packed);
    degxw_kernel<<<NBK, XW_B, 0, stream>>>(gcursor, packed, x, Wc, dinv, h2);
    agg_kernel<<<NBK, AG_B, 0, stream>>>(gcursor, packed, h2, dinv, bc, W1, b1, W2, b2,
                                         W3, b3, out);
}